// Round 1
// baseline (439.613 us; speedup 1.0000x reference)
//
#include <hip/hip_runtime.h>
#include <math.h>

#define H 1024
#define V 50257
#define L 512

// ws layout (float offsets)
#define S_SCORES   0        // 512
#define S_ATTN     1024     // 1024
#define S_X        2048     // 1024
#define S_GI       3072     // 3072
#define S_GH       6144     // 3072
#define S_HNEW     9216     // 1024
#define S_LOGITS   10240    // 50257
#define S_PART     60512    // 16*1024
#define S_PARTIALS 76928    // 2*12565
#define S_RED      102064   // 1

#define NB_LOGITS  12565    // ceil(V/4)

__device__ __forceinline__ float dot4(float4 a, float4 b) {
  return a.x*b.x + a.y*b.y + a.z*b.z + a.w*b.w;
}

__device__ __forceinline__ float wred_sum(float v) {
  #pragma unroll
  for (int o = 32; o > 0; o >>= 1) v += __shfl_down(v, o, 64);
  return v;
}

__device__ __forceinline__ float wred_max(float v) {
  #pragma unroll
  for (int o = 32; o > 0; o >>= 1) v = fmaxf(v, __shfl_down(v, o, 64));
  return v;
}

// K1: scores[j] = dot(cat(embed, h0), attn_W[j]) + attn_b[j]; one block per j
__global__ void k_scores(const int* __restrict__ tok, const float* __restrict__ h0,
                         const float* __restrict__ emb, const float* __restrict__ attn_W,
                         const float* __restrict__ attn_b, float* __restrict__ ws) {
  __shared__ float red[4];
  int t = threadIdx.x, lane = t & 63, wid = t >> 6;
  int j = blockIdx.x;
  const float4* wr = (const float4*)(attn_W + (size_t)j * (2 * H));
  const float4* e4 = (const float4*)(emb + (size_t)tok[0] * H);
  const float4* h4 = (const float4*)h0;
  float v = dot4(wr[t], e4[t]) + dot4(wr[256 + t], h4[t]);
  v = wred_sum(v);
  if (lane == 0) red[wid] = v;
  __syncthreads();
  if (t == 0) ws[S_SCORES + j] = red[0] + red[1] + red[2] + red[3] + attn_b[j];
}

// K2: softmax (recomputed per block) + partial attn_applied over 32-row chunks
// grid = 64: blockIdx & 3 = col chunk (256 cols), blockIdx >> 2 = row chunk (32 rows)
__global__ void k_softmax_attn(const float* __restrict__ enc, float* __restrict__ ws,
                               float* __restrict__ out) {
  __shared__ float w[512];
  __shared__ float red[4];
  int t = threadIdx.x, lane = t & 63, wid = t >> 6;
  float s0 = ws[S_SCORES + t], s1 = ws[S_SCORES + 256 + t];
  float m = wred_max(fmaxf(s0, s1));
  if (lane == 0) red[wid] = m;
  __syncthreads();
  m = fmaxf(fmaxf(red[0], red[1]), fmaxf(red[2], red[3]));
  __syncthreads();
  float e0 = expf(s0 - m), e1 = expf(s1 - m);
  float ls = wred_sum(e0 + e1);
  if (lane == 0) red[wid] = ls;
  __syncthreads();
  float inv = 1.0f / (red[0] + red[1] + red[2] + red[3]);
  w[t] = e0 * inv;
  w[256 + t] = e1 * inv;
  __syncthreads();
  if (blockIdx.x == 0) {
    out[V + H + t] = w[t];
    out[V + H + 256 + t] = w[256 + t];
  }
  int cc = blockIdx.x & 3, rc = blockIdx.x >> 2;
  int col = cc * 256 + t;
  int j0 = rc * 32;
  float acc = 0.f;
  #pragma unroll 8
  for (int j = 0; j < 32; ++j) acc += w[j0 + j] * enc[(size_t)(j0 + j) * H + col];
  ws[S_PART + (size_t)rc * H + col] = acc;
}

// K2b: reduce 16 partials -> attn_applied; grid 4
__global__ void k_attn_reduce(float* __restrict__ ws) {
  int col = blockIdx.x * 256 + threadIdx.x;
  float acc = 0.f;
  #pragma unroll
  for (int p = 0; p < 16; ++p) acc += ws[S_PART + (size_t)p * H + col];
  ws[S_ATTN + col] = acc;
}

// K3: x = relu(cat(embed, attn_applied) @ comb_W.T + comb_b); wave per row, grid 256
__global__ void k_comb(const int* __restrict__ tok, const float* __restrict__ emb,
                       const float* __restrict__ comb_W, const float* __restrict__ comb_b,
                       float* __restrict__ ws) {
  int t = threadIdx.x, lane = t & 63, wid = t >> 6;
  int row = blockIdx.x * 4 + wid;
  const float4* wr = (const float4*)(comb_W + (size_t)row * (2 * H));
  const float4* e4 = (const float4*)(emb + (size_t)tok[0] * H);
  const float4* a4 = (const float4*)(ws + S_ATTN);
  float v = 0.f;
  #pragma unroll
  for (int k = 0; k < 4; ++k) v += dot4(wr[lane + 64 * k], e4[lane + 64 * k]);
  #pragma unroll
  for (int k = 0; k < 4; ++k) v += dot4(wr[256 + lane + 64 * k], a4[lane + 64 * k]);
  v = wred_sum(v);
  if (lane == 0) ws[S_X + row] = fmaxf(v + comb_b[row], 0.f);
}

// K4: gi = x @ W_ih.T + b_ih ; gh = h0 @ W_hh.T + b_hh ; wave per row, grid 1536
__global__ void k_gates(const float* __restrict__ h0, const float* __restrict__ W_ih,
                        const float* __restrict__ W_hh, const float* __restrict__ b_ih,
                        const float* __restrict__ b_hh, float* __restrict__ ws) {
  int t = threadIdx.x, lane = t & 63, wid = t >> 6;
  int g = blockIdx.x * 4 + wid;  // 0..6143
  const float* Wp;
  const float4* vec;
  float bias;
  int dst;
  if (g < 3 * H) {
    Wp = W_ih + (size_t)g * H;
    vec = (const float4*)(ws + S_X);
    bias = b_ih[g];
    dst = S_GI + g;
  } else {
    int r = g - 3 * H;
    Wp = W_hh + (size_t)r * H;
    vec = (const float4*)h0;
    bias = b_hh[r];
    dst = S_GH + r;
  }
  const float4* wr = (const float4*)Wp;
  float v = 0.f;
  #pragma unroll
  for (int k = 0; k < 4; ++k) v += dot4(wr[lane + 64 * k], vec[lane + 64 * k]);
  v = wred_sum(v);
  if (lane == 0) ws[dst] = v + bias;
}

// K5: GRU elementwise; grid 4
__global__ void k_gru(const float* __restrict__ h0, float* __restrict__ ws,
                      float* __restrict__ out) {
  int i = blockIdx.x * 256 + threadIdx.x;
  float ir = ws[S_GI + i], iz = ws[S_GI + H + i], in_ = ws[S_GI + 2 * H + i];
  float hr = ws[S_GH + i], hz = ws[S_GH + H + i], hn = ws[S_GH + 2 * H + i];
  float r = 1.f / (1.f + expf(-(ir + hr)));
  float z = 1.f / (1.f + expf(-(iz + hz)));
  float n = tanhf(in_ + r * hn);
  float h = (1.f - z) * n + z * h0[i];
  ws[S_HNEW + i] = h;
  out[V + i] = h;
}

// K6: logits = h_new @ out_W.T + out_b; wave per row + per-block softmax partials
__global__ void k_logits(const float* __restrict__ out_W, const float* __restrict__ out_b,
                         float* __restrict__ ws) {
  __shared__ float hl[H];
  __shared__ float wl[4];
  int t = threadIdx.x, lane = t & 63, wid = t >> 6;
  ((float4*)hl)[t] = ((const float4*)(ws + S_HNEW))[t];
  __syncthreads();
  int row = blockIdx.x * 4 + wid;
  float logit = -INFINITY;
  if (row < V) {
    const float4* wr = (const float4*)(out_W + (size_t)row * H);
    const float4* h4 = (const float4*)hl;
    float v = 0.f;
    #pragma unroll
    for (int k = 0; k < 4; ++k) v += dot4(wr[lane + 64 * k], h4[lane + 64 * k]);
    v = wred_sum(v);
    if (lane == 0) {
      logit = v + out_b[row];
      ws[S_LOGITS + row] = logit;
    }
  }
  if (lane == 0) wl[wid] = logit;
  __syncthreads();
  if (t == 0) {
    float m = fmaxf(fmaxf(wl[0], wl[1]), fmaxf(wl[2], wl[3]));
    float s = 0.f;
    #pragma unroll
    for (int i = 0; i < 4; ++i)
      if (wl[i] != -INFINITY) s += expf(wl[i] - m);
    ws[S_PARTIALS + 2 * blockIdx.x] = m;
    ws[S_PARTIALS + 2 * blockIdx.x + 1] = s;
  }
}

__device__ __forceinline__ void lse_merge(float& m, float& s, float mb, float sb) {
  if (mb == -INFINITY) return;
  if (m == -INFINITY) { m = mb; s = sb; return; }
  if (mb > m) { float tm = m; m = mb; mb = tm; float ts = s; s = sb; sb = ts; }
  s += sb * expf(mb - m);
}

// K7: combine per-block partials -> logsumexp scalar; 1 block
__global__ void k_combine(float* __restrict__ ws) {
  __shared__ float lm[4], lsv[4];
  int t = threadIdx.x, lane = t & 63, wid = t >> 6;
  float m = -INFINITY, s = 0.f;
  for (int i = t; i < NB_LOGITS; i += 256)
    lse_merge(m, s, ws[S_PARTIALS + 2 * i], ws[S_PARTIALS + 2 * i + 1]);
  #pragma unroll
  for (int o = 32; o > 0; o >>= 1) {
    float mb = __shfl_down(m, o, 64);
    float sb = __shfl_down(s, o, 64);
    lse_merge(m, s, mb, sb);
  }
  if (lane == 0) { lm[wid] = m; lsv[wid] = s; }
  __syncthreads();
  if (t == 0) {
    float M = lm[0], S = lsv[0];
    #pragma unroll
    for (int i = 1; i < 4; ++i) lse_merge(M, S, lm[i], lsv[i]);
    ws[S_RED] = M + logf(S);
  }
}

// K8: logp = logits - lse
__global__ void k_logp(const float* __restrict__ ws, float* __restrict__ out) {
  int i = blockIdx.x * 256 + threadIdx.x;
  if (i < V) out[i] = ws[S_LOGITS + i] - ws[S_RED];
}

extern "C" void kernel_launch(void* const* d_in, const int* in_sizes, int n_in,
                              void* d_out, int out_size, void* d_ws, size_t ws_size,
                              hipStream_t stream) {
  const int* tok = (const int*)d_in[0];
  const float* hidden = (const float*)d_in[1];
  const float* enc = (const float*)d_in[2];
  const float* emb = (const float*)d_in[3];
  const float* attn_W = (const float*)d_in[4];
  const float* attn_b = (const float*)d_in[5];
  const float* comb_W = (const float*)d_in[6];
  const float* comb_b = (const float*)d_in[7];
  const float* W_ih = (const float*)d_in[8];
  const float* W_hh = (const float*)d_in[9];
  const float* b_ih = (const float*)d_in[10];
  const float* b_hh = (const float*)d_in[11];
  const float* out_W = (const float*)d_in[12];
  const float* out_b = (const float*)d_in[13];
  float* out = (float*)d_out;
  float* ws = (float*)d_ws;

  hipLaunchKernelGGL(k_scores, dim3(512), dim3(256), 0, stream, tok, hidden, emb, attn_W, attn_b, ws);
  hipLaunchKernelGGL(k_softmax_attn, dim3(64), dim3(256), 0, stream, enc, ws, out);
  hipLaunchKernelGGL(k_attn_reduce, dim3(4), dim3(256), 0, stream, ws);
  hipLaunchKernelGGL(k_comb, dim3(256), dim3(256), 0, stream, tok, emb, comb_W, comb_b, ws);
  hipLaunchKernelGGL(k_gates, dim3(1536), dim3(256), 0, stream, hidden, W_ih, W_hh, b_ih, b_hh, ws);
  hipLaunchKernelGGL(k_gru, dim3(4), dim3(256), 0, stream, hidden, ws, out);
  hipLaunchKernelGGL(k_logits, dim3(NB_LOGITS), dim3(256), 0, stream, out_W, out_b, ws);
  hipLaunchKernelGGL(k_combine, dim3(1), dim3(256), 0, stream, ws);
  hipLaunchKernelGGL(k_logp, dim3((V + 255) / 256), dim3(256), 0, stream, ws, out);
}

// Round 2
// 430.032 us; speedup vs baseline: 1.0223x; 1.0223x over previous
//
#include <hip/hip_runtime.h>
#include <math.h>

#define H 1024
#define V 50257
#define L 512

// ws layout (float offsets)
#define S_SCORES   0        // 512
#define S_X        2048     // 1024
#define S_GI       3072     // 3072
#define S_GH       6144     // 3072
#define S_HNEW     9216     // 1024
#define S_PART     10240    // 16*1024
#define S_PARTIALS 26624    // 2*3142
#define S_RED      33000    // 1

#define NB_LOGITS  3142     // ceil(V/16)

__device__ __forceinline__ float dot4(float4 a, float4 b) {
  return a.x*b.x + a.y*b.y + a.z*b.z + a.w*b.w;
}

__device__ __forceinline__ float wred_sum(float v) {
  #pragma unroll
  for (int o = 32; o > 0; o >>= 1) v += __shfl_down(v, o, 64);
  return v;
}

__device__ __forceinline__ float wred_max(float v) {
  #pragma unroll
  for (int o = 32; o > 0; o >>= 1) v = fmaxf(v, __shfl_down(v, o, 64));
  return v;
}

// K1: scores[j] = dot(cat(embed, h0), attn_W[j]) + attn_b[j]; wave per score, grid 128
__global__ void k_scores(const int* __restrict__ tok, const float* __restrict__ h0,
                         const float* __restrict__ emb, const float* __restrict__ attn_W,
                         const float* __restrict__ attn_b, float* __restrict__ ws) {
  int t = threadIdx.x, lane = t & 63, wid = t >> 6;
  int j = blockIdx.x * 4 + wid;
  const float4* wr = (const float4*)(attn_W + (size_t)j * (2 * H));
  const float4* e4 = (const float4*)(emb + (size_t)tok[0] * H);
  const float4* h4 = (const float4*)h0;
  float v = 0.f;
  #pragma unroll
  for (int k = 0; k < 4; ++k) {
    int idx = lane + 64 * k;
    v += dot4(wr[idx], e4[idx]) + dot4(wr[256 + idx], h4[idx]);
  }
  v = wred_sum(v);
  if (lane == 0) ws[S_SCORES + j] = v + attn_b[j];
}

// K2: softmax (recomputed per block) + partial attn_applied over 32-row chunks
// grid = 64: blockIdx & 3 = col chunk (256 cols), blockIdx >> 2 = row chunk (32 rows)
__global__ void k_softmax_attn(const float* __restrict__ enc, float* __restrict__ ws,
                               float* __restrict__ out) {
  __shared__ float w[512];
  __shared__ float red[4];
  int t = threadIdx.x, lane = t & 63, wid = t >> 6;
  float s0 = ws[S_SCORES + t], s1 = ws[S_SCORES + 256 + t];
  float m = wred_max(fmaxf(s0, s1));
  if (lane == 0) red[wid] = m;
  __syncthreads();
  m = fmaxf(fmaxf(red[0], red[1]), fmaxf(red[2], red[3]));
  __syncthreads();
  float e0 = expf(s0 - m), e1 = expf(s1 - m);
  float ls = wred_sum(e0 + e1);
  if (lane == 0) red[wid] = ls;
  __syncthreads();
  float inv = 1.0f / (red[0] + red[1] + red[2] + red[3]);
  w[t] = e0 * inv;
  w[256 + t] = e1 * inv;
  __syncthreads();
  if (blockIdx.x == 0) {
    out[V + H + t] = w[t];
    out[V + H + 256 + t] = w[256 + t];
  }
  int cc = blockIdx.x & 3, rc = blockIdx.x >> 2;
  int col = cc * 256 + t;
  int j0 = rc * 32;
  float acc = 0.f;
  #pragma unroll 8
  for (int j = 0; j < 32; ++j) acc += w[j0 + j] * enc[(size_t)(j0 + j) * H + col];
  ws[S_PART + (size_t)rc * H + col] = acc;
}

// K3: x = relu(cat(embed, attn_applied) @ comb_W.T + comb_b); wave per row, grid 256
// attn_applied reduced inline from the 16 L2-resident partials.
__global__ void k_comb(const int* __restrict__ tok, const float* __restrict__ emb,
                       const float* __restrict__ comb_W, const float* __restrict__ comb_b,
                       float* __restrict__ ws) {
  int t = threadIdx.x, lane = t & 63, wid = t >> 6;
  int row = blockIdx.x * 4 + wid;
  const float4* wr = (const float4*)(comb_W + (size_t)row * (2 * H));
  const float4* e4 = (const float4*)(emb + (size_t)tok[0] * H);
  const float4* p4 = (const float4*)(ws + S_PART);
  float v = 0.f;
  #pragma unroll
  for (int k = 0; k < 4; ++k) {
    int idx = lane + 64 * k;
    v += dot4(wr[idx], e4[idx]);
    float4 a = make_float4(0.f, 0.f, 0.f, 0.f);
    #pragma unroll
    for (int p = 0; p < 16; ++p) {
      float4 b = p4[p * 256 + idx];
      a.x += b.x; a.y += b.y; a.z += b.z; a.w += b.w;
    }
    v += dot4(wr[256 + idx], a);
  }
  v = wred_sum(v);
  if (lane == 0) ws[S_X + row] = fmaxf(v + comb_b[row], 0.f);
}

// K4: gi = x @ W_ih.T + b_ih ; gh = h0 @ W_hh.T + b_hh ; wave per row, grid 1536
__global__ void k_gates(const float* __restrict__ h0, const float* __restrict__ W_ih,
                        const float* __restrict__ W_hh, const float* __restrict__ b_ih,
                        const float* __restrict__ b_hh, float* __restrict__ ws) {
  int t = threadIdx.x, lane = t & 63, wid = t >> 6;
  int g = blockIdx.x * 4 + wid;  // 0..6143
  const float* Wp;
  const float4* vec;
  float bias;
  int dst;
  if (g < 3 * H) {
    Wp = W_ih + (size_t)g * H;
    vec = (const float4*)(ws + S_X);
    bias = b_ih[g];
    dst = S_GI + g;
  } else {
    int r = g - 3 * H;
    Wp = W_hh + (size_t)r * H;
    vec = (const float4*)h0;
    bias = b_hh[r];
    dst = S_GH + r;
  }
  const float4* wr = (const float4*)Wp;
  float v = 0.f;
  #pragma unroll
  for (int k = 0; k < 4; ++k) v += dot4(wr[lane + 64 * k], vec[lane + 64 * k]);
  v = wred_sum(v);
  if (lane == 0) ws[dst] = v + bias;
}

// K5: GRU elementwise; grid 4
__global__ void k_gru(const float* __restrict__ h0, float* __restrict__ ws,
                      float* __restrict__ out) {
  int i = blockIdx.x * 256 + threadIdx.x;
  float ir = ws[S_GI + i], iz = ws[S_GI + H + i], in_ = ws[S_GI + 2 * H + i];
  float hr = ws[S_GH + i], hz = ws[S_GH + H + i], hn = ws[S_GH + 2 * H + i];
  float r = 1.f / (1.f + expf(-(ir + hr)));
  float z = 1.f / (1.f + expf(-(iz + hz)));
  float n = tanhf(in_ + r * hn);
  float h = (1.f - z) * n + z * h0[i];
  ws[S_HNEW + i] = h;
  out[V + i] = h;
}

// K6: logits = h_new @ out_W.T + out_b written straight into out[0..V);
// 16 rows per block (4 per wave), per-block softmax partial (m,s) to ws.
__global__ void k_logits(const float* __restrict__ out_W, const float* __restrict__ out_b,
                         float* __restrict__ ws, float* __restrict__ out) {
  __shared__ float hl[H];
  __shared__ float wl[16];
  int t = threadIdx.x, lane = t & 63, wid = t >> 6;
  ((float4*)hl)[t] = ((const float4*)(ws + S_HNEW))[t];
  __syncthreads();
  const float4* h4 = (const float4*)hl;
  int base = blockIdx.x * 16 + wid * 4;
  float lg[4];
  #pragma unroll
  for (int r = 0; r < 4; ++r) {
    int row = base + r;
    float v = 0.f;
    if (row < V) {
      const float4* wr = (const float4*)(out_W + (size_t)row * H);
      #pragma unroll
      for (int k = 0; k < 4; ++k) {
        int idx = lane + 64 * k;
        v += dot4(wr[idx], h4[idx]);
      }
    }
    v = wred_sum(v);
    lg[r] = -INFINITY;
    if (lane == 0 && row < V) {
      lg[r] = v + out_b[row];
      out[row] = lg[r];
    }
  }
  if (lane == 0) {
    #pragma unroll
    for (int r = 0; r < 4; ++r) wl[wid * 4 + r] = lg[r];
  }
  __syncthreads();
  if (t == 0) {
    float m = -INFINITY;
    #pragma unroll
    for (int i = 0; i < 16; ++i) m = fmaxf(m, wl[i]);
    float s = 0.f;
    #pragma unroll
    for (int i = 0; i < 16; ++i)
      if (wl[i] != -INFINITY) s += expf(wl[i] - m);
    ws[S_PARTIALS + 2 * blockIdx.x] = m;
    ws[S_PARTIALS + 2 * blockIdx.x + 1] = s;
  }
}

__device__ __forceinline__ void lse_merge(float& m, float& s, float mb, float sb) {
  if (mb == -INFINITY) return;
  if (m == -INFINITY) { m = mb; s = sb; return; }
  if (mb > m) { float tm = m; m = mb; mb = tm; float ts = s; s = sb; sb = ts; }
  s += sb * expf(mb - m);
}

// K7: combine per-block partials -> logsumexp scalar; 1 block
__global__ void k_combine(float* __restrict__ ws) {
  __shared__ float lm[4], lsv[4];
  int t = threadIdx.x, lane = t & 63, wid = t >> 6;
  float m = -INFINITY, s = 0.f;
  for (int i = t; i < NB_LOGITS; i += 256)
    lse_merge(m, s, ws[S_PARTIALS + 2 * i], ws[S_PARTIALS + 2 * i + 1]);
  #pragma unroll
  for (int o = 32; o > 0; o >>= 1) {
    float mb = __shfl_down(m, o, 64);
    float sb = __shfl_down(s, o, 64);
    lse_merge(m, s, mb, sb);
  }
  if (lane == 0) { lm[wid] = m; lsv[wid] = s; }
  __syncthreads();
  if (t == 0) {
    float M = lm[0], S = lsv[0];
    #pragma unroll
    for (int i = 1; i < 4; ++i) lse_merge(M, S, lm[i], lsv[i]);
    ws[S_RED] = M + logf(S);
  }
}

// K8: logp = logits - lse (in place on out[0..V))
__global__ void k_logp(const float* __restrict__ ws, float* __restrict__ out) {
  int i = blockIdx.x * 256 + threadIdx.x;
  if (i < V) out[i] -= ws[S_RED];
}

extern "C" void kernel_launch(void* const* d_in, const int* in_sizes, int n_in,
                              void* d_out, int out_size, void* d_ws, size_t ws_size,
                              hipStream_t stream) {
  const int* tok = (const int*)d_in[0];
  const float* hidden = (const float*)d_in[1];
  const float* enc = (const float*)d_in[2];
  const float* emb = (const float*)d_in[3];
  const float* attn_W = (const float*)d_in[4];
  const float* attn_b = (const float*)d_in[5];
  const float* comb_W = (const float*)d_in[6];
  const float* comb_b = (const float*)d_in[7];
  const float* W_ih = (const float*)d_in[8];
  const float* W_hh = (const float*)d_in[9];
  const float* b_ih = (const float*)d_in[10];
  const float* b_hh = (const float*)d_in[11];
  const float* out_W = (const float*)d_in[12];
  const float* out_b = (const float*)d_in[13];
  float* out = (float*)d_out;
  float* ws = (float*)d_ws;

  hipLaunchKernelGGL(k_scores, dim3(128), dim3(256), 0, stream, tok, hidden, emb, attn_W, attn_b, ws);
  hipLaunchKernelGGL(k_softmax_attn, dim3(64), dim3(256), 0, stream, enc, ws, out);
  hipLaunchKernelGGL(k_comb, dim3(256), dim3(256), 0, stream, tok, emb, comb_W, comb_b, ws);
  hipLaunchKernelGGL(k_gates, dim3(1536), dim3(256), 0, stream, hidden, W_ih, W_hh, b_ih, b_hh, ws);
  hipLaunchKernelGGL(k_gru, dim3(4), dim3(256), 0, stream, hidden, ws, out);
  hipLaunchKernelGGL(k_logits, dim3(NB_LOGITS), dim3(256), 0, stream, out_W, out_b, ws, out);
  hipLaunchKernelGGL(k_combine, dim3(1), dim3(256), 0, stream, ws);
  hipLaunchKernelGGL(k_logp, dim3((V + 255) / 256), dim3(256), 0, stream, ws, out);
}

// Round 3
// 428.409 us; speedup vs baseline: 1.0262x; 1.0038x over previous
//
#include <hip/hip_runtime.h>
#include <math.h>

#define H 1024
#define V 50257
#define L 512

// ws layout (float offsets)
#define S_SCORES   0        // 512
#define S_X        2048     // 1024
#define S_HNEW     9216     // 1024
#define S_PART     10240    // 16*1024
#define S_PARTIALS 26624    // 2*3142
#define S_RED      33000    // 1

#define NB_LOGITS  3142     // ceil(V/16)

__device__ __forceinline__ float dot4(float4 a, float4 b) {
  return a.x*b.x + a.y*b.y + a.z*b.z + a.w*b.w;
}

__device__ __forceinline__ float wred_sum(float v) {
  #pragma unroll
  for (int o = 32; o > 0; o >>= 1) v += __shfl_down(v, o, 64);
  return v;
}

__device__ __forceinline__ float wred_max(float v) {
  #pragma unroll
  for (int o = 32; o > 0; o >>= 1) v = fmaxf(v, __shfl_down(v, o, 64));
  return v;
}

// K1: scores[j] = dot(cat(embed, h0), attn_W[j]) + attn_b[j]; wave per score, grid 128
__global__ void k_scores(const int* __restrict__ tok, const float* __restrict__ h0,
                         const float* __restrict__ emb, const float* __restrict__ attn_W,
                         const float* __restrict__ attn_b, float* __restrict__ ws) {
  int t = threadIdx.x, lane = t & 63, wid = t >> 6;
  int j = blockIdx.x * 4 + wid;
  const float4* wr = (const float4*)(attn_W + (size_t)j * (2 * H));
  const float4* e4 = (const float4*)(emb + (size_t)tok[0] * H);
  const float4* h4 = (const float4*)h0;
  float v = 0.f;
  #pragma unroll
  for (int k = 0; k < 4; ++k) {
    int idx = lane + 64 * k;
    v += dot4(wr[idx], e4[idx]) + dot4(wr[256 + idx], h4[idx]);
  }
  v = wred_sum(v);
  if (lane == 0) ws[S_SCORES + j] = v + attn_b[j];
}

// K2: softmax (recomputed per block) + partial attn_applied over 32-row chunks
// grid = 64: blockIdx & 3 = col chunk (256 cols), blockIdx >> 2 = row chunk (32 rows)
__global__ void k_softmax_attn(const float* __restrict__ enc, float* __restrict__ ws,
                               float* __restrict__ out) {
  __shared__ float w[512];
  __shared__ float red[4];
  int t = threadIdx.x, lane = t & 63, wid = t >> 6;
  float s0 = ws[S_SCORES + t], s1 = ws[S_SCORES + 256 + t];
  float m = wred_max(fmaxf(s0, s1));
  if (lane == 0) red[wid] = m;
  __syncthreads();
  m = fmaxf(fmaxf(red[0], red[1]), fmaxf(red[2], red[3]));
  __syncthreads();
  float e0 = expf(s0 - m), e1 = expf(s1 - m);
  float ls = wred_sum(e0 + e1);
  if (lane == 0) red[wid] = ls;
  __syncthreads();
  float inv = 1.0f / (red[0] + red[1] + red[2] + red[3]);
  w[t] = e0 * inv;
  w[256 + t] = e1 * inv;
  __syncthreads();
  if (blockIdx.x == 0) {
    out[V + H + t] = w[t];
    out[V + H + 256 + t] = w[256 + t];
  }
  int cc = blockIdx.x & 3, rc = blockIdx.x >> 2;
  int col = cc * 256 + t;
  int j0 = rc * 32;
  float acc = 0.f;
  #pragma unroll 8
  for (int j = 0; j < 32; ++j) acc += w[j0 + j] * enc[(size_t)(j0 + j) * H + col];
  ws[S_PART + (size_t)rc * H + col] = acc;
}

// K3: x = relu(cat(embed, attn_applied) @ comb_W.T + comb_b); wave per row, grid 256
// attn_applied reduced inline from the 16 L2-resident partials.
__global__ void k_comb(const int* __restrict__ tok, const float* __restrict__ emb,
                       const float* __restrict__ comb_W, const float* __restrict__ comb_b,
                       float* __restrict__ ws) {
  int t = threadIdx.x, lane = t & 63, wid = t >> 6;
  int row = blockIdx.x * 4 + wid;
  const float4* wr = (const float4*)(comb_W + (size_t)row * (2 * H));
  const float4* e4 = (const float4*)(emb + (size_t)tok[0] * H);
  const float4* p4 = (const float4*)(ws + S_PART);
  float v = 0.f;
  #pragma unroll
  for (int k = 0; k < 4; ++k) {
    int idx = lane + 64 * k;
    v += dot4(wr[idx], e4[idx]);
    float4 a = make_float4(0.f, 0.f, 0.f, 0.f);
    #pragma unroll
    for (int p = 0; p < 16; ++p) {
      float4 b = p4[p * 256 + idx];
      a.x += b.x; a.y += b.y; a.z += b.z; a.w += b.w;
    }
    v += dot4(wr[256 + idx], a);
  }
  v = wred_sum(v);
  if (lane == 0) ws[S_X + row] = fmaxf(v + comb_b[row], 0.f);
}

// K4: fused gates+GRU. Wave per hidden index i: 6 dots (W_ih rows i,H+i,2H+i
// against x; W_hh rows against h0), then GRU elementwise on lane 0. grid 256.
__global__ void k_gru_fused(const float* __restrict__ h0, const float* __restrict__ W_ih,
                            const float* __restrict__ W_hh, const float* __restrict__ b_ih,
                            const float* __restrict__ b_hh, float* __restrict__ ws,
                            float* __restrict__ out) {
  int t = threadIdx.x, lane = t & 63, wid = t >> 6;
  int i = blockIdx.x * 4 + wid;  // 0..1023
  const float4* x4 = (const float4*)(ws + S_X);
  const float4* h4 = (const float4*)h0;
  const float4* wi_r = (const float4*)(W_ih + (size_t)i * H);
  const float4* wi_z = (const float4*)(W_ih + (size_t)(H + i) * H);
  const float4* wi_n = (const float4*)(W_ih + (size_t)(2 * H + i) * H);
  const float4* wh_r = (const float4*)(W_hh + (size_t)i * H);
  const float4* wh_z = (const float4*)(W_hh + (size_t)(H + i) * H);
  const float4* wh_n = (const float4*)(W_hh + (size_t)(2 * H + i) * H);
  float sir = 0.f, siz = 0.f, sin_ = 0.f, shr = 0.f, shz = 0.f, shn = 0.f;
  #pragma unroll
  for (int k = 0; k < 4; ++k) {
    int idx = lane + 64 * k;
    float4 xv = x4[idx], hv = h4[idx];
    sir  += dot4(wi_r[idx], xv);
    siz  += dot4(wi_z[idx], xv);
    sin_ += dot4(wi_n[idx], xv);
    shr  += dot4(wh_r[idx], hv);
    shz  += dot4(wh_z[idx], hv);
    shn  += dot4(wh_n[idx], hv);
  }
  sir = wred_sum(sir); siz = wred_sum(siz); sin_ = wred_sum(sin_);
  shr = wred_sum(shr); shz = wred_sum(shz); shn = wred_sum(shn);
  if (lane == 0) {
    float ir = sir + b_ih[i], iz = siz + b_ih[H + i], in_ = sin_ + b_ih[2 * H + i];
    float hr = shr + b_hh[i], hz = shz + b_hh[H + i], hn = shn + b_hh[2 * H + i];
    float r = 1.f / (1.f + expf(-(ir + hr)));
    float z = 1.f / (1.f + expf(-(iz + hz)));
    float n = tanhf(in_ + r * hn);
    float h = (1.f - z) * n + z * h0[i];
    ws[S_HNEW + i] = h;
    out[V + i] = h;
  }
}

// K5: logits = h_new @ out_W.T + out_b written straight into out[0..V);
// 16 rows per block (4 per wave), per-block softmax partial (m,s) to ws.
__global__ void k_logits(const float* __restrict__ out_W, const float* __restrict__ out_b,
                         float* __restrict__ ws, float* __restrict__ out) {
  __shared__ float hl[H];
  __shared__ float wl[16];
  int t = threadIdx.x, lane = t & 63, wid = t >> 6;
  ((float4*)hl)[t] = ((const float4*)(ws + S_HNEW))[t];
  __syncthreads();
  const float4* h4 = (const float4*)hl;
  int base = blockIdx.x * 16 + wid * 4;
  float lg[4];
  #pragma unroll
  for (int r = 0; r < 4; ++r) {
    int row = base + r;
    float v = 0.f;
    if (row < V) {
      const float4* wr = (const float4*)(out_W + (size_t)row * H);
      #pragma unroll
      for (int k = 0; k < 4; ++k) {
        int idx = lane + 64 * k;
        v += dot4(wr[idx], h4[idx]);
      }
    }
    v = wred_sum(v);
    lg[r] = -INFINITY;
    if (lane == 0 && row < V) {
      lg[r] = v + out_b[row];
      out[row] = lg[r];
    }
  }
  if (lane == 0) {
    #pragma unroll
    for (int r = 0; r < 4; ++r) wl[wid * 4 + r] = lg[r];
  }
  __syncthreads();
  if (t == 0) {
    float m = -INFINITY;
    #pragma unroll
    for (int i = 0; i < 16; ++i) m = fmaxf(m, wl[i]);
    float s = 0.f;
    #pragma unroll
    for (int i = 0; i < 16; ++i)
      if (wl[i] != -INFINITY) s += expf(wl[i] - m);
    ws[S_PARTIALS + 2 * blockIdx.x] = m;
    ws[S_PARTIALS + 2 * blockIdx.x + 1] = s;
  }
}

__device__ __forceinline__ void lse_merge(float& m, float& s, float mb, float sb) {
  if (mb == -INFINITY) return;
  if (m == -INFINITY) { m = mb; s = sb; return; }
  if (mb > m) { float tm = m; m = mb; mb = tm; float ts = s; s = sb; sb = ts; }
  s += sb * expf(mb - m);
}

// K6: each block redundantly combines partials -> lse, then logp = logits - lse.
__global__ void k_logp(const float* __restrict__ ws, float* __restrict__ out) {
  __shared__ float lm[4], lsv[4];
  int t = threadIdx.x, lane = t & 63, wid = t >> 6;
  float m = -INFINITY, s = 0.f;
  for (int i = t; i < NB_LOGITS; i += 256)
    lse_merge(m, s, ws[S_PARTIALS + 2 * i], ws[S_PARTIALS + 2 * i + 1]);
  #pragma unroll
  for (int o = 32; o > 0; o >>= 1) {
    float mb = __shfl_down(m, o, 64);
    float sb = __shfl_down(s, o, 64);
    lse_merge(m, s, mb, sb);
  }
  if (lane == 0) { lm[wid] = m; lsv[wid] = s; }
  __syncthreads();
  float M = lm[0], S = lsv[0];
  #pragma unroll
  for (int i = 1; i < 4; ++i) lse_merge(M, S, lm[i], lsv[i]);
  float lse = M + logf(S);
  int i = blockIdx.x * 256 + t;
  if (i < V) out[i] -= lse;
}

extern "C" void kernel_launch(void* const* d_in, const int* in_sizes, int n_in,
                              void* d_out, int out_size, void* d_ws, size_t ws_size,
                              hipStream_t stream) {
  const int* tok = (const int*)d_in[0];
  const float* hidden = (const float*)d_in[1];
  const float* enc = (const float*)d_in[2];
  const float* emb = (const float*)d_in[3];
  const float* attn_W = (const float*)d_in[4];
  const float* attn_b = (const float*)d_in[5];
  const float* comb_W = (const float*)d_in[6];
  const float* comb_b = (const float*)d_in[7];
  const float* W_ih = (const float*)d_in[8];
  const float* W_hh = (const float*)d_in[9];
  const float* b_ih = (const float*)d_in[10];
  const float* b_hh = (const float*)d_in[11];
  const float* out_W = (const float*)d_in[12];
  const float* out_b = (const float*)d_in[13];
  float* out = (float*)d_out;
  float* ws = (float*)d_ws;

  hipLaunchKernelGGL(k_scores, dim3(128), dim3(256), 0, stream, tok, hidden, emb, attn_W, attn_b, ws);
  hipLaunchKernelGGL(k_softmax_attn, dim3(64), dim3(256), 0, stream, enc, ws, out);
  hipLaunchKernelGGL(k_comb, dim3(256), dim3(256), 0, stream, tok, emb, comb_W, comb_b, ws);
  hipLaunchKernelGGL(k_gru_fused, dim3(256), dim3(256), 0, stream, hidden, W_ih, W_hh, b_ih, b_hh, ws, out);
  hipLaunchKernelGGL(k_logits, dim3(NB_LOGITS), dim3(256), 0, stream, out_W, out_b, ws, out);
  hipLaunchKernelGGL(k_logp, dim3((V + 255) / 256), dim3(256), 0, stream, ws, out);
}